// Round 1
// baseline (95.655 us; speedup 1.0000x reference)
//
#include <hip/hip_runtime.h>
#include <hip/hip_bf16.h>
#include <stdint.h>

// Problem constants
#define NB    32768          // batches
#define S     11
#define DD    128
#define HH    32
#define ROWS  (NB * S)       // 360448
#define RPB   128            // rows per block in g_kernel
#define XSTR  136            // bf16 elems per LDS x-row (128 + 8 pad)

__device__ __forceinline__ unsigned short f2bf(float f) {
    unsigned u = __float_as_uint(f);
    unsigned r = u + 0x7fffu + ((u >> 16) & 1u);
    return (unsigned short)(r >> 16);
}

// g[r,o] = relu(x_r @ W1 + b1) @ (Wv@Wo) [o]  + (pos[s] @ Wv@Wo)[o],  s = r % 11
__global__ __launch_bounds__(256) void g_kernel(
    const float* __restrict__ x, const float* __restrict__ W1,
    const float* __restrict__ b1, const float* __restrict__ Wv,
    const float* __restrict__ pos, const float* __restrict__ Wo,
    float* __restrict__ g)
{
    __shared__ unsigned short x_bf[RPB * XSTR];   // 34816 B
    __shared__ float w1_lds[DD * HH];             // 16384 B
    __shared__ float b1_lds[HH];
    __shared__ float M_lds[HH * 2];
    __shared__ float posM_lds[S * 2];

    const int t   = threadIdx.x;
    const int blk = blockIdx.x;

    // ---- stage x chunk (128 rows x 128 f32) as bf16 into padded LDS ----
    const float4* xsrc = (const float4*)(x + (size_t)blk * (RPB * DD));
    for (int i = t; i < RPB * DD / 4; i += 256) {
        float4 v = xsrc[i];
        int row = i >> 5;          // 32 float4 per row
        int d4  = i & 31;
        ushort4 bv;
        bv.x = f2bf(v.x); bv.y = f2bf(v.y); bv.z = f2bf(v.z); bv.w = f2bf(v.w);
        *(ushort4*)&x_bf[row * XSTR + d4 * 4] = bv;
    }
    // ---- stage W1 (row-major [d][j], matches global layout) ----
    for (int i = t; i < DD * HH / 4; i += 256)
        ((float4*)w1_lds)[i] = ((const float4*)W1)[i];
    if (t < HH) b1_lds[t] = b1[t];
    // ---- M = Wv @ Wo  (32x2) ----
    if (t < 64) {
        int j = t >> 1, o = t & 1;
        float s = 0.f;
        for (int k = 0; k < HH; ++k) s += Wv[j * HH + k] * Wo[k * 2 + o];
        M_lds[j * 2 + o] = s;
    }
    // ---- posM = pos_enc @ Wv @ Wo  (11x2), independent recompute ----
    if (t >= 64 && t < 64 + 22) {
        int i2 = t - 64, sp = i2 >> 1, o = i2 & 1;
        float acc = 0.f;
        for (int j = 0; j < HH; ++j) {
            float m = 0.f;
            for (int k = 0; k < HH; ++k) m += Wv[j * HH + k] * Wo[k * 2 + o];
            acc += pos[sp * HH + j] * m;
        }
        posM_lds[i2] = acc;
    }
    __syncthreads();

    // ---- compute: thread (rg,cg) does rows rg+32p (p<4), cols cg*4..+3 ----
    const int rg = t >> 3, cg = t & 7, j0 = cg * 4;
    float acc[4][4] = {};
    #pragma unroll 4
    for (int d4 = 0; d4 < 32; ++d4) {
        float w[4][4];
        #pragma unroll
        for (int dd = 0; dd < 4; ++dd)
            *(float4*)w[dd] = *(const float4*)&w1_lds[(d4 * 4 + dd) * HH + j0];
        #pragma unroll
        for (int p = 0; p < 4; ++p) {
            uint2 xb = *(const uint2*)&x_bf[(rg + 32 * p) * XSTR + d4 * 4];
            float x0 = __uint_as_float(xb.x << 16);
            float x1 = __uint_as_float(xb.x & 0xffff0000u);
            float x2 = __uint_as_float(xb.y << 16);
            float x3 = __uint_as_float(xb.y & 0xffff0000u);
            #pragma unroll
            for (int c = 0; c < 4; ++c) {
                acc[p][c] = fmaf(x0, w[0][c],
                            fmaf(x1, w[1][c],
                            fmaf(x2, w[2][c],
                            fmaf(x3, w[3][c], acc[p][c]))));
            }
        }
    }

    // ---- relu + @M, reduce partial g over the 8 cg lanes ----
    float pg[4][2];
    #pragma unroll
    for (int p = 0; p < 4; ++p) {
        float s0 = 0.f, s1 = 0.f;
        #pragma unroll
        for (int c = 0; c < 4; ++c) {
            float y = fmaxf(acc[p][c] + b1_lds[j0 + c], 0.f);
            s0 += y * M_lds[(j0 + c) * 2 + 0];
            s1 += y * M_lds[(j0 + c) * 2 + 1];
        }
        pg[p][0] = s0; pg[p][1] = s1;
    }
    #pragma unroll
    for (int off = 1; off < 8; off <<= 1) {
        #pragma unroll
        for (int p = 0; p < 4; ++p) {
            pg[p][0] += __shfl_xor(pg[p][0], off);
            pg[p][1] += __shfl_xor(pg[p][1], off);
        }
    }
    if (cg < 2) {
        #pragma unroll
        for (int p = 0; p < 4; ++p) {
            int row = blk * RPB + rg + 32 * p;
            int s   = row % S;
            g[row * 2 + cg] = pg[p][cg] + posM_lds[s * 2 + cg];
        }
    }
}

// out1[b,t,o] = bo[o] + sum_{u in [t-5, t+5] clipped to [0,10]} g[b,u,o]
__global__ __launch_bounds__(256) void out_kernel(
    const float* __restrict__ g, const float* __restrict__ bo,
    float* __restrict__ out1)
{
    int idx = blockIdx.x * 256 + threadIdx.x;       // (b,t), exactly ROWS
    int b = idx / S, tt = idx - b * S;
    const float2* gb = (const float2*)(g + (size_t)b * (2 * S));
    int lo = tt - 5 < 0 ? 0 : tt - 5;
    int hi = tt + 5 > S - 1 ? S - 1 : tt + 5;
    float s0 = bo[0], s1 = bo[1];
    for (int u = lo; u <= hi; ++u) { float2 v = gb[u]; s0 += v.x; s1 += v.y; }
    ((float2*)out1)[idx] = make_float2(s0, s1);
}

// attn_w == softmax over a singleton dim == 1.0 everywhere
__global__ __launch_bounds__(256) void ones_kernel(float4* __restrict__ p)
{
    int i = blockIdx.x * 256 + threadIdx.x;
    p[i] = make_float4(1.f, 1.f, 1.f, 1.f);
}

extern "C" void kernel_launch(void* const* d_in, const int* in_sizes, int n_in,
                              void* d_out, int out_size, void* d_ws, size_t ws_size,
                              hipStream_t stream)
{
    const float* x   = (const float*)d_in[0];
    const float* W1  = (const float*)d_in[1];
    const float* b1  = (const float*)d_in[2];
    // d_in[3] = Wq, d_in[4] = Wk: dead code (softmax over singleton dim)
    const float* Wv  = (const float*)d_in[5];
    const float* pos = (const float*)d_in[6];
    const float* Wo  = (const float*)d_in[7];
    const float* bo  = (const float*)d_in[8];

    float* out1 = (float*)d_out;                 // 720896 floats (B,S,O)
    float* attn = out1 + (size_t)ROWS * 2;       // 3965952 floats (B,S,1,WIN)

    // scratch for g (ROWS x 2 f32); fall back to attn region (overwritten later)
    float* g = (ws_size >= (size_t)ROWS * 2 * sizeof(float)) ? (float*)d_ws : attn;

    g_kernel  <<<ROWS / RPB, 256, 0, stream>>>(x, W1, b1, Wv, pos, Wo, g);
    out_kernel<<<ROWS / 256, 256, 0, stream>>>(g, bo, out1);
    ones_kernel<<<(ROWS * S) / 4 / 256, 256, 0, stream>>>((float4*)attn);
}